// Round 1
// baseline (1353.758 us; speedup 1.0000x reference)
//
#include <hip/hip_runtime.h>
#include <stdint.h>

#define B_ 2
#define T_ 2048
#define C_ 256
#define H_ 4
#define L_ 4
#define FF 1024
#define V_ 32000

typedef short bfrag __attribute__((ext_vector_type(8)));   // 8 x bf16 (MFMA A/B operand)
typedef float facc  __attribute__((ext_vector_type(4)));   // MFMA C/D
typedef short s4v   __attribute__((ext_vector_type(4)));
typedef short s8v   __attribute__((ext_vector_type(8)));
typedef unsigned short u16;

#define FLAG_BIAS 1
#define FLAG_RES  2
#define FLAG_RELU 4
#define FLAG_BF16 8

struct OMap {
  long long zb, zh, rb, rt, cs;
  int zs, zm, rs, rm;
  // idx = (z>>zs)*zb + (z&zm)*zh + (r>>rs)*rb + (r&rm)*rt + c*cs
};

__device__ __forceinline__ u16 f2bf(float f) {
  uint32_t x = __float_as_uint(f);
  return (u16)((x + 0x7fffu + ((x >> 16) & 1u)) >> 16);
}
__device__ __forceinline__ float bf2f(u16 u) {
  return __uint_as_float(((uint32_t)u) << 16);
}

__device__ __forceinline__ void gload_lds16(const void* g, void* l) {
  __builtin_amdgcn_global_load_lds(
      (const __attribute__((address_space(1))) uint32_t*)g,
      (__attribute__((address_space(3))) uint32_t*)l, 16, 0, 0);
}

// ---------------------------------------------------------------- transpose
// in: fp32 [R,Cc] (batch z, stride R*Cc) -> out: bf16 [Cc,R] (same z stride)
__global__ __launch_bounds__(256) void transpose_k(const float* __restrict__ in,
                                                   u16* __restrict__ out,
                                                   int R, int Cc) {
  __shared__ float tile[32][33];
  long long zo = (long long)blockIdx.z * R * Cc;
  int c0 = blockIdx.x * 32, r0 = blockIdx.y * 32;
  int tx = threadIdx.x & 31, ty = threadIdx.x >> 5;  // 8 x 32
#pragma unroll
  for (int i = ty; i < 32; i += 8)
    tile[i][tx] = in[zo + (long long)(r0 + i) * Cc + (c0 + tx)];
  __syncthreads();
#pragma unroll
  for (int i = ty; i < 32; i += 8)
    out[zo + (long long)(c0 + i) * R + (r0 + tx)] = f2bf(tile[tx][i]);
}

// ---------------------------------------------------------------- embedding
__global__ void embed_k(const int* __restrict__ tok, const float* __restrict__ emb,
                        const float* __restrict__ pos, float* __restrict__ x) {
  int r = blockIdx.x, c = threadIdx.x;
  int t = r & (T_ - 1);
  x[(long long)r * C_ + c] =
      emb[(long long)tok[r] * C_ + c] + pos[(long long)t * C_ + c];
}

// ---------------------------------------------------------------- layernorm
// wave per row; writes fp32 residual stream AND bf16 copy for GEMM input
__global__ __launch_bounds__(256) void layernorm_k(const float* xin, float* xout,
                                                   u16* __restrict__ xnout,
                                                   const float* __restrict__ g,
                                                   const float* __restrict__ b) {
  int wid = threadIdx.x >> 6, lane = threadIdx.x & 63;
  int row = blockIdx.x * 4 + wid;
  float4 v = ((const float4*)(xin + (long long)row * C_))[lane];
  float s = v.x + v.y + v.z + v.w;
#pragma unroll
  for (int o = 32; o > 0; o >>= 1) s += __shfl_xor(s, o);
  float mean = s * (1.f / 256.f);
  float d0 = v.x - mean, d1 = v.y - mean, d2 = v.z - mean, d3 = v.w - mean;
  float q2 = d0 * d0 + d1 * d1 + d2 * d2 + d3 * d3;
#pragma unroll
  for (int o = 32; o > 0; o >>= 1) q2 += __shfl_xor(q2, o);
  float rstd = rsqrtf(q2 * (1.f / 256.f) + 1e-5f);
  float4 gv = ((const float4*)g)[lane];
  float4 bv = ((const float4*)b)[lane];
  float y0 = d0 * rstd * gv.x + bv.x;
  float y1 = d1 * rstd * gv.y + bv.y;
  float y2 = d2 * rstd * gv.z + bv.z;
  float y3 = d3 * rstd * gv.w + bv.w;
  float4 yo; yo.x = y0; yo.y = y1; yo.z = y2; yo.w = y3;
  ((float4*)(xout + (long long)row * C_))[lane] = yo;
  u16 tmp[4] = {f2bf(y0), f2bf(y1), f2bf(y2), f2bf(y3)};
  *(s4v*)&xnout[(long long)row * C_ + lane * 4] = *(const s4v*)tmp;
}

// ---------------------------------------------------------------- softmax (causal)
// wave per row of scores [B*H*T, T] bf16; in-place probs; chunk-skip masked 512-col chunks
__global__ __launch_bounds__(256) void softmax_k(u16* __restrict__ sc) {
  int wid = threadIdx.x >> 6, lane = threadIdx.x & 63;
  long long row = (long long)blockIdx.x * 4 + wid;
  int t = (int)(row & (T_ - 1));
  u16* p = sc + row * T_;
  float v[32];
  float m = -3.4e38f;
#pragma unroll
  for (int j = 0; j < 4; ++j) {
    if (j * 512 <= t) {
      s8v raw = *(const s8v*)&p[j * 512 + lane * 8];
#pragma unroll
      for (int e = 0; e < 8; ++e) {
        int s = j * 512 + lane * 8 + e;
        float val = bf2f((u16)raw[e]) * 0.0625f;
        val = (s <= t) ? val : -3.4e38f;
        v[j * 8 + e] = val;
        m = fmaxf(m, val);
      }
    } else {
#pragma unroll
      for (int e = 0; e < 8; ++e) v[j * 8 + e] = -3.4e38f;
    }
  }
#pragma unroll
  for (int o = 32; o > 0; o >>= 1) m = fmaxf(m, __shfl_xor(m, o));
  float sum = 0.f;
#pragma unroll
  for (int i = 0; i < 32; ++i) {
    float e = (v[i] > -1e38f) ? __expf(v[i] - m) : 0.f;
    v[i] = e;
    sum += e;
  }
#pragma unroll
  for (int o = 32; o > 0; o >>= 1) sum += __shfl_xor(sum, o);
  float r = 1.f / sum;
#pragma unroll
  for (int j = 0; j < 4; ++j) {
    if (j * 512 <= t) {   // == "chunk < causal K-limit of this 128-row block"
      u16 tmp[8];
#pragma unroll
      for (int e = 0; e < 8; ++e) tmp[e] = f2bf(v[j * 8 + e] * r);
      *(s8v*)&p[j * 512 + lane * 8] = *(const s8v*)tmp;
    }
  }
}

// ---------------------------------------------------------------- GEMM (NT)
// C[M,N] = A[M,K] @ Bt[N,K]^T ; 128x128 tile, BK=32, 4 waves, global_load_lds staging
__global__ __launch_bounds__(256) void gemm_nt(
    const u16* __restrict__ A, long long az, int lda,
    const u16* __restrict__ B, long long bz, int ldb,
    int K, void* outp, OMap om,
    const float* __restrict__ bias, const float* res,
    int flags, int causal) {
  __shared__ u16 As[128 * 32];
  __shared__ u16 Bs[128 * 32];
  int gx = blockIdx.x, gy = blockIdx.y, z = blockIdx.z;
  if (causal == 1 && gx > gy) return;  // fully-masked score block
  int kend = K;
  if (causal == 2) { int kl = (gy + 1) * 128; kend = kl < K ? kl : K; }
  const u16* Ab = A + (long long)z * az + (long long)gy * 128 * lda;
  const u16* Bb = B + (long long)z * bz + (long long)gx * 128 * ldb;
  int tid = threadIdx.x;
  int lane = tid & 63, wid = tid >> 6;
  int wr = (wid >> 1) * 64, wc = (wid & 1) * 64;
  int srow = tid >> 2, scol = (tid & 3) * 8;

  facc acc[4][4];
  facc zf = {0.f, 0.f, 0.f, 0.f};
#pragma unroll
  for (int m = 0; m < 4; ++m)
#pragma unroll
    for (int n = 0; n < 4; ++n) acc[m][n] = zf;

  for (int k0 = 0; k0 < kend; k0 += 32) {
    gload_lds16(Ab + (long long)srow * lda + k0 + scol, &As[srow * 32 + scol]);
    gload_lds16(Ab + (long long)(srow + 64) * lda + k0 + scol, &As[(srow + 64) * 32 + scol]);
    gload_lds16(Bb + (long long)srow * ldb + k0 + scol, &Bs[srow * 32 + scol]);
    gload_lds16(Bb + (long long)(srow + 64) * ldb + k0 + scol, &Bs[(srow + 64) * 32 + scol]);
    __syncthreads();  // drains vmcnt (compiler emits waitcnt before s_barrier)
    int kk = (lane >> 4) * 8;
    int ar = wr + (lane & 15);
    int br = wc + (lane & 15);
    bfrag af[4], bfv[4];
#pragma unroll
    for (int m = 0; m < 4; ++m) af[m] = *(const bfrag*)&As[(ar + m * 16) * 32 + kk];
#pragma unroll
    for (int n = 0; n < 4; ++n) bfv[n] = *(const bfrag*)&Bs[(br + n * 16) * 32 + kk];
#pragma unroll
    for (int m = 0; m < 4; ++m)
#pragma unroll
      for (int n = 0; n < 4; ++n)
        acc[m][n] = __builtin_amdgcn_mfma_f32_16x16x32_bf16(af[m], bfv[n], acc[m][n], 0, 0, 0);
    __syncthreads();
  }

  int rg = (lane >> 4) * 4;
  int cl = lane & 15;
#pragma unroll
  for (int m = 0; m < 4; ++m) {
#pragma unroll
    for (int n = 0; n < 4; ++n) {
      int c_abs = gx * 128 + wc + n * 16 + cl;
      float bvv = (flags & FLAG_BIAS) ? bias[c_abs] : 0.f;
#pragma unroll
      for (int i = 0; i < 4; ++i) {
        int r = gy * 128 + wr + m * 16 + rg + i;
        float val = acc[m][n][i] + bvv;
        long long oi = (long long)(z >> om.zs) * om.zb
                     + (long long)(z & om.zm) * om.zh
                     + (long long)((unsigned)r >> om.rs) * om.rb
                     + (long long)(r & om.rm) * om.rt
                     + (long long)c_abs * om.cs;
        if (flags & FLAG_RES) val += res[oi];
        if (flags & FLAG_RELU) val = fmaxf(val, 0.f);
        if (flags & FLAG_BF16) ((u16*)outp)[oi] = f2bf(val);
        else ((float*)outp)[oi] = val;
      }
    }
  }
}

// ---------------------------------------------------------------- launch
extern "C" void kernel_launch(void* const* d_in, const int* in_sizes, int n_in,
                              void* d_out, int out_size, void* d_ws, size_t ws_size,
                              hipStream_t stream) {
  (void)in_sizes; (void)n_in; (void)out_size; (void)ws_size;
  const int*   tokens = (const int*)d_in[0];
  const float* embed  = (const float*)d_in[1];
  const float* pos    = (const float*)d_in[2];
  const float* ln1_g  = (const float*)d_in[3];
  const float* ln1_b  = (const float*)d_in[4];
  const float* wq     = (const float*)d_in[5];
  const float* wk     = (const float*)d_in[6];
  const float* wv     = (const float*)d_in[7];
  const float* wo     = (const float*)d_in[8];
  const float* wo_b   = (const float*)d_in[9];
  const float* ln2_g  = (const float*)d_in[10];
  const float* ln2_b  = (const float*)d_in[11];
  const float* w1     = (const float*)d_in[12];
  const float* b1     = (const float*)d_in[13];
  const float* w2     = (const float*)d_in[14];
  const float* b2     = (const float*)d_in[15];
  const float* lnf_g  = (const float*)d_in[16];
  const float* lnf_b  = (const float*)d_in[17];
  const float* wf     = (const float*)d_in[18];
  const float* bf     = (const float*)d_in[19];
  float* out = (float*)d_out;

  char* ws = (char*)d_ws;
  size_t off = 0;
  auto alloc = [&](size_t bytes) -> char* {
    char* p = ws + off;
    off += (bytes + 255) & ~(size_t)255;
    return p;
  };
  const long long NR = (long long)B_ * T_;  // 4096 rows
  float* x  = (float*)alloc(NR * C_ * 4);
  u16* xn   = (u16*)alloc(NR * C_ * 2);
  u16* q    = (u16*)alloc((long long)B_ * H_ * T_ * C_ * 2);
  u16* k    = (u16*)alloc((long long)B_ * H_ * T_ * C_ * 2);
  u16* vt   = (u16*)alloc((long long)B_ * H_ * C_ * T_ * 2);
  u16* sc   = (u16*)alloc((long long)B_ * H_ * T_ * T_ * 2);
  u16* ocat = (u16*)alloc(NR * (long long)(H_ * C_) * 2);
  u16* hdn  = (u16*)alloc(NR * (long long)FF * 2);
  u16* wqT  = (u16*)alloc((long long)L_ * H_ * C_ * C_ * 2);
  u16* wkT  = (u16*)alloc((long long)L_ * H_ * C_ * C_ * 2);
  u16* wvT  = (u16*)alloc((long long)L_ * H_ * C_ * C_ * 2);
  u16* woT  = (u16*)alloc((long long)L_ * C_ * (H_ * C_) * 2);
  u16* w1T  = (u16*)alloc((long long)L_ * FF * C_ * 2);
  u16* w2T  = (u16*)alloc((long long)L_ * C_ * FF * 2);
  u16* wfT  = (u16*)alloc((long long)V_ * C_ * 2);

  dim3 tb(256);
  // weight transposes (fp32 [K,N] -> bf16 [N,K])
  transpose_k<<<dim3(8, 8, 16), tb, 0, stream>>>(wq, wqT, 256, 256);
  transpose_k<<<dim3(8, 8, 16), tb, 0, stream>>>(wk, wkT, 256, 256);
  transpose_k<<<dim3(8, 8, 16), tb, 0, stream>>>(wv, wvT, 256, 256);
  transpose_k<<<dim3(8, 32, 4), tb, 0, stream>>>(wo, woT, 1024, 256);
  transpose_k<<<dim3(32, 8, 4), tb, 0, stream>>>(w1, w1T, 256, 1024);
  transpose_k<<<dim3(8, 32, 4), tb, 0, stream>>>(w2, w2T, 1024, 256);
  transpose_k<<<dim3(1000, 8, 1), tb, 0, stream>>>(wf, wfT, 256, 32000);

  embed_k<<<dim3(4096), tb, 0, stream>>>(tokens, embed, pos, x);

  const long long TC  = (long long)T_ * C_;
  const long long TT2 = (long long)T_ * T_;
  const long long HTC = (long long)H_ * T_ * C_;
  const long long THC = (long long)T_ * H_ * C_;
  OMap om_qk  = {0, TC, HTC, C_, 1, 30, 3, 11, 2047};
  OMap om_v   = {0, TC, HTC, 1, T_, 30, 3, 11, 2047};
  OMap om_s   = {0, TT2, 0, T_, 1, 30, 15, 30, 0x7fffffff};
  OMap om_pv  = {THC, C_, 0, H_ * C_, 1, 2, 3, 30, 0x7fffffff};
  OMap om_x   = {0, 0, 0, C_, 1, 30, 0, 30, 0x7fffffff};
  OMap om_ff  = {0, 0, 0, FF, 1, 30, 0, 30, 0x7fffffff};
  OMap om_out = {0, 0, 0, V_, 1, 30, 0, 30, 0x7fffffff};

  for (int l = 0; l < L_; ++l) {
    layernorm_k<<<dim3(1024), tb, 0, stream>>>(x, x, xn, ln1_g + l * C_, ln1_b + l * C_);
    // QKV (z = head)
    gemm_nt<<<dim3(2, 32, 4), tb, 0, stream>>>(
        xn, 0, C_, wqT + (long long)l * H_ * C_ * C_, (long long)C_ * C_, C_,
        C_, q, om_qk, nullptr, nullptr, FLAG_BF16, 0);
    gemm_nt<<<dim3(2, 32, 4), tb, 0, stream>>>(
        xn, 0, C_, wkT + (long long)l * H_ * C_ * C_, (long long)C_ * C_, C_,
        C_, k, om_qk, nullptr, nullptr, FLAG_BF16, 0);
    gemm_nt<<<dim3(2, 32, 4), tb, 0, stream>>>(
        xn, 0, C_, wvT + (long long)l * H_ * C_ * C_, (long long)C_ * C_, C_,
        C_, vt, om_v, nullptr, nullptr, FLAG_BF16, 0);
    // scores = Q @ K^T (z = b*H+h), skip fully-masked blocks
    gemm_nt<<<dim3(16, 16, 8), tb, 0, stream>>>(
        q, TC, C_, k, TC, C_, C_, sc, om_s, nullptr, nullptr, FLAG_BF16, 1);
    softmax_k<<<dim3(4096), tb, 0, stream>>>(sc);
    // O = P @ V (K-limited by causality), write into concat layout [4096, H*C]
    gemm_nt<<<dim3(2, 16, 8), tb, 0, stream>>>(
        sc, TT2, T_, vt, TC, T_, T_, ocat, om_pv, nullptr, nullptr, FLAG_BF16, 2);
    // x = x + ocat @ wo + wo_b   (fp32 out, residual)
    gemm_nt<<<dim3(2, 32, 1), tb, 0, stream>>>(
        ocat, 0, H_ * C_, woT + (long long)l * C_ * H_ * C_, 0, H_ * C_,
        H_ * C_, x, om_x, wo_b + l * C_, x, FLAG_BIAS | FLAG_RES, 0);
    layernorm_k<<<dim3(1024), tb, 0, stream>>>(x, x, xn, ln2_g + l * C_, ln2_b + l * C_);
    // hdn = relu(xn @ w1 + b1)
    gemm_nt<<<dim3(8, 32, 1), tb, 0, stream>>>(
        xn, 0, C_, w1T + (long long)l * FF * C_, 0, C_,
        C_, hdn, om_ff, b1 + l * FF, nullptr, FLAG_BIAS | FLAG_RELU | FLAG_BF16, 0);
    // x = x + hdn @ w2 + b2
    gemm_nt<<<dim3(2, 32, 1), tb, 0, stream>>>(
        hdn, 0, FF, w2T + (long long)l * C_ * FF, 0, FF,
        FF, x, om_x, b2 + l * C_, x, FLAG_BIAS | FLAG_RES, 0);
  }
  layernorm_k<<<dim3(1024), tb, 0, stream>>>(x, x, xn, lnf_g, lnf_b);
  // logits = xn @ wf + bf  (fp32 out)
  gemm_nt<<<dim3(250, 32, 1), tb, 0, stream>>>(
      xn, 0, C_, wfT, 0, C_, C_, out, om_out, bf, nullptr, FLAG_BIAS, 0);
}

// Round 2
// 1004.207 us; speedup vs baseline: 1.3481x; 1.3481x over previous
//
#include <hip/hip_runtime.h>
#include <stdint.h>

#define B_ 2
#define T_ 2048
#define C_ 256
#define H_ 4
#define L_ 4
#define FF 1024
#define V_ 32000

typedef short bfrag __attribute__((ext_vector_type(8)));   // 8 x bf16 (MFMA A/B operand)
typedef float facc  __attribute__((ext_vector_type(4)));   // MFMA C/D
typedef short s4v   __attribute__((ext_vector_type(4)));
typedef short s8v   __attribute__((ext_vector_type(8)));
typedef unsigned short u16;

#define FLAG_BIAS 1
#define FLAG_RES  2
#define FLAG_RELU 4
#define FLAG_BF16 8

struct OMap {
  long long zb, zh, rb, rt, cs;
  int zs, zm, rs, rm;
  // idx = (z>>zs)*zb + (z&zm)*zh + (r>>rs)*rb + (r&rm)*rt + c*cs
};
struct ZMap {
  long long hi, lo;
  int zs, zm;  // off = (z>>zs)*hi + (z&zm)*lo
};

__device__ __forceinline__ u16 f2bf(float f) {
  uint32_t x = __float_as_uint(f);
  return (u16)((x + 0x7fffu + ((x >> 16) & 1u)) >> 16);
}
__device__ __forceinline__ float bf2f(u16 u) {
  return __uint_as_float(((uint32_t)u) << 16);
}

__device__ __forceinline__ void gload_lds16(const void* g, void* l) {
  __builtin_amdgcn_global_load_lds(
      (const __attribute__((address_space(1))) uint32_t*)g,
      (__attribute__((address_space(3))) uint32_t*)l, 16, 0, 0);
}

// ---------------------------------------------------------------- transpose (f32 -> bf16)
__global__ __launch_bounds__(256) void transpose_k(const float* __restrict__ in,
                                                   u16* __restrict__ out,
                                                   int R, int Cc, ZMap oz) {
  __shared__ float tile[32][33];
  long long zi = (long long)blockIdx.z * R * Cc;
  int z = blockIdx.z;
  long long zo = (long long)(z >> oz.zs) * oz.hi + (long long)(z & oz.zm) * oz.lo;
  int c0 = blockIdx.x * 32, r0 = blockIdx.y * 32;
  int tx = threadIdx.x & 31, ty = threadIdx.x >> 5;  // 8 x 32
#pragma unroll
  for (int i = ty; i < 32; i += 8)
    tile[i][tx] = in[zi + (long long)(r0 + i) * Cc + (c0 + tx)];
  __syncthreads();
#pragma unroll
  for (int i = ty; i < 32; i += 8)
    out[zo + (long long)(c0 + i) * R + (r0 + tx)] = f2bf(tile[tx][i]);
}

// ---------------------------------------------------------------- V transpose (u16)
__global__ __launch_bounds__(256) void transpose_v(const u16* __restrict__ qkv,
                                                   u16* __restrict__ vt) {
  __shared__ u16 tile[32][33];
  int z = blockIdx.z, b = z >> 2, h = z & 3;
  const u16* in = qkv + (long long)b * T_ * 3072 + 2048 + h * 256;
  int t0 = blockIdx.x * 32, d0 = blockIdx.y * 32;
  int tx = threadIdx.x & 31, ty = threadIdx.x >> 5;
#pragma unroll
  for (int i = ty; i < 32; i += 8)
    tile[i][tx] = in[(long long)(t0 + i) * 3072 + (d0 + tx)];
  __syncthreads();
#pragma unroll
  for (int i = ty; i < 32; i += 8)
    vt[((long long)z * 256 + d0 + i) * T_ + (t0 + tx)] = tile[tx][i];
}

// ---------------------------------------------------------------- embedding
__global__ void embed_k(const int* __restrict__ tok, const float* __restrict__ emb,
                        const float* __restrict__ pos, float* __restrict__ x) {
  int r = blockIdx.x, c = threadIdx.x;
  int t = r & (T_ - 1);
  x[(long long)r * C_ + c] =
      emb[(long long)tok[r] * C_ + c] + pos[(long long)t * C_ + c];
}

// ---------------------------------------------------------------- layernorm
__global__ __launch_bounds__(256) void layernorm_k(const float* xin, float* xout,
                                                   u16* __restrict__ xnout,
                                                   const float* __restrict__ g,
                                                   const float* __restrict__ b) {
  int wid = threadIdx.x >> 6, lane = threadIdx.x & 63;
  int row = blockIdx.x * 4 + wid;
  float4 v = ((const float4*)(xin + (long long)row * C_))[lane];
  float s = v.x + v.y + v.z + v.w;
#pragma unroll
  for (int o = 32; o > 0; o >>= 1) s += __shfl_xor(s, o);
  float mean = s * (1.f / 256.f);
  float d0 = v.x - mean, d1 = v.y - mean, d2 = v.z - mean, d3 = v.w - mean;
  float q2 = d0 * d0 + d1 * d1 + d2 * d2 + d3 * d3;
#pragma unroll
  for (int o = 32; o > 0; o >>= 1) q2 += __shfl_xor(q2, o);
  float rstd = rsqrtf(q2 * (1.f / 256.f) + 1e-5f);
  float4 gv = ((const float4*)g)[lane];
  float4 bv = ((const float4*)b)[lane];
  float y0 = d0 * rstd * gv.x + bv.x;
  float y1 = d1 * rstd * gv.y + bv.y;
  float y2 = d2 * rstd * gv.z + bv.z;
  float y3 = d3 * rstd * gv.w + bv.w;
  float4 yo; yo.x = y0; yo.y = y1; yo.z = y2; yo.w = y3;
  ((float4*)(xout + (long long)row * C_))[lane] = yo;
  u16 tmp[4] = {f2bf(y0), f2bf(y1), f2bf(y2), f2bf(y3)};
  *(s4v*)&xnout[(long long)row * C_ + lane * 4] = *(const s4v*)tmp;
}

// ---------------------------------------------------------------- softmax (causal)
__global__ __launch_bounds__(256) void softmax_k(u16* __restrict__ sc) {
  int wid = threadIdx.x >> 6, lane = threadIdx.x & 63;
  long long row = (long long)blockIdx.x * 4 + wid;
  int t = (int)(row & (T_ - 1));
  u16* p = sc + row * T_;
  float v[32];
  float m = -3.4e38f;
#pragma unroll
  for (int j = 0; j < 4; ++j) {
    if (j * 512 <= t) {
      s8v raw = *(const s8v*)&p[j * 512 + lane * 8];
#pragma unroll
      for (int e = 0; e < 8; ++e) {
        int s = j * 512 + lane * 8 + e;
        float val = bf2f((u16)raw[e]) * 0.0625f;
        val = (s <= t) ? val : -3.4e38f;
        v[j * 8 + e] = val;
        m = fmaxf(m, val);
      }
    } else {
#pragma unroll
      for (int e = 0; e < 8; ++e) v[j * 8 + e] = -3.4e38f;
    }
  }
#pragma unroll
  for (int o = 32; o > 0; o >>= 1) m = fmaxf(m, __shfl_xor(m, o));
  float sum = 0.f;
#pragma unroll
  for (int i = 0; i < 32; ++i) {
    float e = (v[i] > -1e38f) ? __expf(v[i] - m) : 0.f;
    v[i] = e;
    sum += e;
  }
#pragma unroll
  for (int o = 32; o > 0; o >>= 1) sum += __shfl_xor(sum, o);
  float r = 1.f / sum;
#pragma unroll
  for (int j = 0; j < 4; ++j) {
    if (j * 512 <= t) {
      u16 tmp[8];
#pragma unroll
      for (int e = 0; e < 8; ++e) tmp[e] = f2bf(v[j * 8 + e] * r);
      *(s8v*)&p[j * 512 + lane * 8] = *(const s8v*)tmp;
    }
  }
}

// ---------------------------------------------------------------- GEMM (NT), templated tile
template <int BM, int BN>
__global__ __launch_bounds__(256) void gemm_nt(
    const u16* __restrict__ A, ZMap za, int lda,
    const u16* __restrict__ B, ZMap zb, int ldb,
    int K, void* outp, OMap om,
    const float* __restrict__ bias, const float* res,
    int flags, int causal) {
  constexpr int MR = BM / 32, NR = BN / 32;
  __shared__ u16 As[BM * 32];
  __shared__ u16 Bs[BN * 32];
  int gx = blockIdx.x, gy = blockIdx.y, z = blockIdx.z;
  if (causal == 1 && gx * BN > gy * BM + BM - 1) return;
  int kend = K;
  if (causal == 2) { int kl = (gy + 1) * BM; kend = kl < K ? kl : K; }
  const u16* Ab = A + (long long)(z >> za.zs) * za.hi + (long long)(z & za.zm) * za.lo
                + (long long)gy * BM * lda;
  const u16* Bb = B + (long long)(z >> zb.zs) * zb.hi + (long long)(z & zb.zm) * zb.lo
                + (long long)gx * BN * ldb;
  int tid = threadIdx.x;
  int lane = tid & 63, wid = tid >> 6;
  int wr = (wid >> 1) * (BM / 2), wc = (wid & 1) * (BN / 2);
  int srow = tid >> 2, scol = (tid & 3) * 8;

  facc acc[MR][NR];
  facc zf = {0.f, 0.f, 0.f, 0.f};
#pragma unroll
  for (int m = 0; m < MR; ++m)
#pragma unroll
    for (int n = 0; n < NR; ++n) acc[m][n] = zf;

  for (int k0 = 0; k0 < kend; k0 += 32) {
#pragma unroll
    for (int i = 0; i < BM / 64; ++i)
      gload_lds16(Ab + (long long)(srow + i * 64) * lda + k0 + scol,
                  &As[(srow + i * 64) * 32 + scol]);
#pragma unroll
    for (int i = 0; i < BN / 64; ++i)
      gload_lds16(Bb + (long long)(srow + i * 64) * ldb + k0 + scol,
                  &Bs[(srow + i * 64) * 32 + scol]);
    __syncthreads();
    int kk = (lane >> 4) * 8;
    int ar = wr + (lane & 15);
    int br = wc + (lane & 15);
    bfrag af[MR], bfv[NR];
#pragma unroll
    for (int m = 0; m < MR; ++m) af[m] = *(const bfrag*)&As[(ar + m * 16) * 32 + kk];
#pragma unroll
    for (int n = 0; n < NR; ++n) bfv[n] = *(const bfrag*)&Bs[(br + n * 16) * 32 + kk];
#pragma unroll
    for (int m = 0; m < MR; ++m)
#pragma unroll
      for (int n = 0; n < NR; ++n)
        acc[m][n] = __builtin_amdgcn_mfma_f32_16x16x32_bf16(af[m], bfv[n], acc[m][n], 0, 0, 0);
    __syncthreads();
  }

  int rg = (lane >> 4) * 4;
  int cl = lane & 15;
#pragma unroll
  for (int m = 0; m < MR; ++m) {
#pragma unroll
    for (int n = 0; n < NR; ++n) {
      int c_abs = gx * BN + wc + n * 16 + cl;
      float bvv = (flags & FLAG_BIAS) ? bias[c_abs] : 0.f;
#pragma unroll
      for (int i = 0; i < 4; ++i) {
        int r = gy * BM + wr + m * 16 + rg + i;
        float val = acc[m][n][i] + bvv;
        long long oi = (long long)(z >> om.zs) * om.zb
                     + (long long)(z & om.zm) * om.zh
                     + (long long)((unsigned)r >> om.rs) * om.rb
                     + (long long)(r & om.rm) * om.rt
                     + (long long)c_abs * om.cs;
        if (flags & FLAG_RES) val += res[oi];
        if (flags & FLAG_RELU) val = fmaxf(val, 0.f);
        if (flags & FLAG_BF16) ((u16*)outp)[oi] = f2bf(val);
        else ((float*)outp)[oi] = val;
      }
    }
  }
}

// ---------------------------------------------------------------- launch
extern "C" void kernel_launch(void* const* d_in, const int* in_sizes, int n_in,
                              void* d_out, int out_size, void* d_ws, size_t ws_size,
                              hipStream_t stream) {
  (void)in_sizes; (void)n_in; (void)out_size; (void)ws_size;
  const int*   tokens = (const int*)d_in[0];
  const float* embed  = (const float*)d_in[1];
  const float* pos    = (const float*)d_in[2];
  const float* ln1_g  = (const float*)d_in[3];
  const float* ln1_b  = (const float*)d_in[4];
  const float* wq     = (const float*)d_in[5];
  const float* wk     = (const float*)d_in[6];
  const float* wv     = (const float*)d_in[7];
  const float* wo     = (const float*)d_in[8];
  const float* wo_b   = (const float*)d_in[9];
  const float* ln2_g  = (const float*)d_in[10];
  const float* ln2_b  = (const float*)d_in[11];
  const float* w1     = (const float*)d_in[12];
  const float* b1     = (const float*)d_in[13];
  const float* w2     = (const float*)d_in[14];
  const float* b2     = (const float*)d_in[15];
  const float* lnf_g  = (const float*)d_in[16];
  const float* lnf_b  = (const float*)d_in[17];
  const float* wf     = (const float*)d_in[18];
  const float* bf     = (const float*)d_in[19];
  float* out = (float*)d_out;

  char* ws = (char*)d_ws;
  size_t off = 0;
  auto alloc = [&](size_t bytes) -> char* {
    char* p = ws + off;
    off += (bytes + 255) & ~(size_t)255;
    return p;
  };
  const long long NR = (long long)B_ * T_;  // 4096 rows
  float* x   = (float*)alloc(NR * C_ * 4);
  u16* xn    = (u16*)alloc(NR * C_ * 2);
  u16* qkv   = (u16*)alloc(NR * 3072LL * 2);
  u16* vt    = (u16*)alloc((long long)B_ * H_ * C_ * T_ * 2);
  u16* sc    = (u16*)alloc((long long)B_ * H_ * T_ * T_ * 2);
  u16* ocat  = (u16*)alloc(NR * (long long)(H_ * C_) * 2);
  u16* hdn   = (u16*)alloc(NR * (long long)FF * 2);
  u16* wqkvT = (u16*)alloc((long long)L_ * 3 * H_ * C_ * C_ * 2);
  u16* woT   = (u16*)alloc((long long)L_ * C_ * (H_ * C_) * 2);
  u16* w1T   = (u16*)alloc((long long)L_ * FF * C_ * 2);
  u16* w2T   = (u16*)alloc((long long)L_ * C_ * FF * 2);
  u16* wfT   = (u16*)alloc((long long)V_ * C_ * 2);

  dim3 tb(256);
  ZMap z0    = {0, 0, 30, 0};
  ZMap zqkvW = {3 * 1024 * 256, 256 * 256, 2, 3};
  ZMap zsimp = {0, 262144, 30, 0x7fffffff};
  ZMap zqkvA = {(long long)T_ * 3072, 256, 2, 3};
  ZMap zsc   = {0, (long long)T_ * T_, 30, 0x7fffffff};
  ZMap zvt   = {0, (long long)C_ * T_, 30, 0x7fffffff};

  transpose_k<<<dim3(8, 8, 16), tb, 0, stream>>>(wq, wqkvT, 256, 256, zqkvW);
  transpose_k<<<dim3(8, 8, 16), tb, 0, stream>>>(wk, wqkvT + 1024 * 256, 256, 256, zqkvW);
  transpose_k<<<dim3(8, 8, 16), tb, 0, stream>>>(wv, wqkvT + 2048 * 256, 256, 256, zqkvW);
  transpose_k<<<dim3(8, 32, 4), tb, 0, stream>>>(wo, woT, 1024, 256, zsimp);
  transpose_k<<<dim3(32, 8, 4), tb, 0, stream>>>(w1, w1T, 256, 1024, zsimp);
  transpose_k<<<dim3(8, 32, 4), tb, 0, stream>>>(w2, w2T, 1024, 256, zsimp);
  transpose_k<<<dim3(1000, 8, 1), tb, 0, stream>>>(wf, wfT, 256, 32000, z0);

  embed_k<<<dim3(4096), tb, 0, stream>>>(tokens, embed, pos, x);

  const long long TT2 = (long long)T_ * T_;
  const long long THC = (long long)T_ * H_ * C_;
  OMap om_qkv = {0, 0, 0, 3072, 1, 30, 0, 30, 0x7fffffff};
  OMap om_s   = {0, TT2, 0, T_, 1, 30, 15, 30, 0x7fffffff};
  OMap om_pv  = {THC, C_, 0, H_ * C_, 1, 2, 3, 30, 0x7fffffff};
  OMap om_x   = {0, 0, 0, C_, 1, 30, 0, 30, 0x7fffffff};
  OMap om_ff  = {0, 0, 0, FF, 1, 30, 0, 30, 0x7fffffff};
  OMap om_out = {0, 0, 0, V_, 1, 30, 0, 30, 0x7fffffff};

  for (int l = 0; l < L_; ++l) {
    layernorm_k<<<dim3(1024), tb, 0, stream>>>(x, x, xn, ln1_g + l * C_, ln1_b + l * C_);
    gemm_nt<128, 128><<<dim3(24, 32, 1), tb, 0, stream>>>(
        xn, z0, C_, wqkvT + (long long)l * 3 * 1024 * 256, z0, C_,
        C_, qkv, om_qkv, nullptr, nullptr, FLAG_BF16, 0);
    transpose_v<<<dim3(64, 8, 8), tb, 0, stream>>>(qkv, vt);
    gemm_nt<128, 128><<<dim3(16, 16, 8), tb, 0, stream>>>(
        qkv, zqkvA, 3072, qkv + 1024, zqkvA, 3072, C_, sc, om_s,
        nullptr, nullptr, FLAG_BF16, 1);
    softmax_k<<<dim3(4096), tb, 0, stream>>>(sc);
    gemm_nt<64, 64><<<dim3(4, 32, 8), tb, 0, stream>>>(
        sc, zsc, T_, vt, zvt, T_, T_, ocat, om_pv, nullptr, nullptr, FLAG_BF16, 2);
    gemm_nt<64, 64><<<dim3(4, 64, 1), tb, 0, stream>>>(
        ocat, z0, H_ * C_, woT + (long long)l * C_ * H_ * C_, z0, H_ * C_,
        H_ * C_, x, om_x, wo_b + l * C_, x, FLAG_BIAS | FLAG_RES, 0);
    layernorm_k<<<dim3(1024), tb, 0, stream>>>(x, x, xn, ln2_g + l * C_, ln2_b + l * C_);
    gemm_nt<64, 64><<<dim3(16, 64, 1), tb, 0, stream>>>(
        xn, z0, C_, w1T + (long long)l * FF * C_, z0, C_,
        C_, hdn, om_ff, b1 + l * FF, nullptr, FLAG_BIAS | FLAG_RELU | FLAG_BF16, 0);
    gemm_nt<64, 64><<<dim3(4, 64, 1), tb, 0, stream>>>(
        hdn, z0, FF, w2T + (long long)l * C_ * FF, z0, FF,
        FF, x, om_x, b2 + l * C_, x, FLAG_BIAS | FLAG_RES, 0);
  }
  layernorm_k<<<dim3(1024), tb, 0, stream>>>(x, x, xn, lnf_g, lnf_b);
  gemm_nt<128, 128><<<dim3(250, 32, 1), tb, 0, stream>>>(
      xn, z0, C_, wfT, z0, C_, C_, out, om_out, bf, nullptr, FLAG_BIAS, 0);
}